// Round 10
// baseline (399.327 us; speedup 1.0000x reference)
//
#include <hip/hip_runtime.h>
#include <math.h>

// Problem constants
#define B_   4096
#define N_   64
#define SS_  5
#define I_   7
#define H_   256
#define M1_  512
#define M2_  512
#define A_   81

typedef _Float16 f16;
typedef f16   f16x8 __attribute__((ext_vector_type(8)));
typedef float f32x4 __attribute__((ext_vector_type(4)));
typedef int   i32x4 __attribute__((ext_vector_type(4)));

__device__ __forceinline__ void fma4(float4& a, float s, const float4 w) {
  a.x = fmaf(s, w.x, a.x);
  a.y = fmaf(s, w.y, a.y);
  a.z = fmaf(s, w.z, a.z);
  a.w = fmaf(s, w.w, a.w);
}

__device__ __forceinline__ float4 relu4(float4 v) {
  v.x = fmaxf(v.x, 0.f); v.y = fmaxf(v.y, 0.f);
  v.z = fmaxf(v.z, 0.f); v.w = fmaxf(v.w, 0.f);
  return v;
}

__device__ __forceinline__ float sigm_(float x) {
  return __builtin_amdgcn_rcpf(1.f + __expf(-x));
}
__device__ __forceinline__ float tanh_(float x) {
  return 1.f - 2.f * __builtin_amdgcn_rcpf(__expf(2.f * x) + 1.f);
}

// ---------------------------------------------------------------------------
// Kernel 0: pack weights. One WAVE per packed column p (1024 waves).
// p = w*128 + ct*16 + l15 view; gate decomposition p = w*128 + g*32 + uu.
// Wq[kt][p][k32] i8 with per-column scale mx = max|col|:
//   Wq = round(W * 127/mx)            (W ≈ Wq·mx/127)
// scd[p]    = mx/127^2                (i32 -> gate dequant, × sh)
// bsum_p[p] = b_ih+b_hh;  Wxk[p][8] f16 x-weights (j<7 real, j=7 zero).
// ---------------------------------------------------------------------------
__global__ __launch_bounds__(1024) void pack_weights(
    const float* __restrict__ W_ih,
    const float* __restrict__ W_hh,
    const float* __restrict__ b_ih,
    const float* __restrict__ b_hh,
    signed char* __restrict__ Wq,
    f16* __restrict__ Wxk,
    float* __restrict__ bsum_p,
    float* __restrict__ scd) {
  const int gtid = blockIdx.x * 1024 + threadIdx.x;
  const int p    = gtid >> 6;           // one wave per column
  const int lane = gtid & 63;
  const int w = p >> 7, r = p & 127, g = r >> 5, uu = r & 31;
  const int row = g * H_ + w * 32 + uu;

  // lane owns k = lane*4 .. lane*4+3 (coalesced float4)
  const float4 v4 = *(const float4*)(W_hh + row * H_ + lane * 4);
  float mx = fmaxf(fmaxf(fabsf(v4.x), fabsf(v4.y)),
                   fmaxf(fabsf(v4.z), fabsf(v4.w)));
  #pragma unroll
  for (int off = 32; off; off >>= 1)
    mx = fmaxf(mx, __shfl_xor(mx, off));
  mx = fmaxf(mx, 1e-12f);
  const float is = 127.f / mx;

  // quantize own 4 values, pack to one dword
  int b0i = (int)rintf(v4.x * is), b1i = (int)rintf(v4.y * is);
  int b2i = (int)rintf(v4.z * is), b3i = (int)rintf(v4.w * is);
  b0i = max(-127, min(127, b0i)); b1i = max(-127, min(127, b1i));
  b2i = max(-127, min(127, b2i)); b3i = max(-127, min(127, b3i));
  const unsigned int packed = (b0i & 0xff) | ((b1i & 0xff) << 8) |
                              ((b2i & 0xff) << 16) | ((b3i & 0xff) << 24);
  const int kt  = lane >> 3;            // (lane*4)/32
  const int k32 = (lane & 7) * 4;
  *(unsigned int*)(Wq + kt * 32768 + p * 32 + k32) = packed;

  if (lane < 8)  Wxk[p * 8 + lane] = (lane < I_) ? (f16)W_ih[row * I_ + lane] : (f16)0.f;
  if (lane == 8)  bsum_p[p]  = b_ih[row] + b_hh[row];
  if (lane == 9)  scd[p]     = mx * (1.f / 16129.f);   // mx/127^2
}

// ---------------------------------------------------------------------------
// Kernel 1: distance + stable descending rank-sort + gather.
// xbuf: f16 [blk][rank(64)][bi(16)][8]; selfbuf: f32 [B][5].
// ---------------------------------------------------------------------------
__global__ void sort_gather(const float* __restrict__ state,
                            f16* __restrict__ xbuf,
                            float* __restrict__ selfbuf) {
  const int b = blockIdx.x;
  const int e = threadIdx.x;                 // 0..63, one wave
  const float* row = state + ((size_t)b * N_ + e) * 12;
  const float4* r4 = (const float4*)row;
  const float4 v0 = r4[0], v1 = r4[1], v2 = r4[2];
  float s[12];
  s[0]=v0.x; s[1]=v0.y; s[2]=v0.z;  s[3]=v0.w;
  s[4]=v1.x; s[5]=v1.y; s[6]=v1.z;  s[7]=v1.w;
  s[8]=v2.x; s[9]=v2.y; s[10]=v2.z; s[11]=v2.w;

  const float s5 = s[5], s6 = s[6];
  const float d = (s5 != 0.f && s6 != 0.f) ? sqrtf(s5 * s5 + s6 * s6) : INFINITY;

  __shared__ float dd[64];
  dd[e] = d;
  __syncthreads();

  int rank = 0;
  #pragma unroll
  for (int j = 0; j < 64; ++j) {
    const float dj = dd[j];
    rank += (dj > d || (dj == d && j < e)) ? 1 : 0;
  }

  f16* xo = xbuf + (((size_t)(b >> 4) * 64 + rank) * 16 + (b & 15)) * 8;
  #pragma unroll
  for (int f = 0; f < I_; ++f) xo[f] = (f16)s[SS_ + f];
  xo[7] = (f16)0.f;

  if (e == 0) {
    #pragma unroll
    for (int i = 0; i < SS_; ++i) selfbuf[b * SS_ + i] = s[i];
  }
}

// ---------------------------------------------------------------------------
// Kernel 2: i8 MFMA LSTM, AGPR-resident W_hh. 256 blocks x 512 threads (8
// waves = 2/SIMD, 1 block/CU), 16 batches/block. Wave w owns packed cols
// [128w,128w+128): ALL 8 k-tiles as i8 B-frags pinned in AGPRs ("+a" asm —
// the unused accumulator file; MFMA reads B from AGPR directly on gfx950).
// h quantized i8 with per-block per-step dynamic scale sh (block max|h|).
// Gates: facc = cvt(i32acc)·(mx·sh/127^2) + (bias + x@W_ih via f16 MFMA).
// All 64 steps of x staged in LDS once.
// LDS: xall 16384 + Bx 16384 + hq 5120 + wmax 32 = ~37.9 KB.
// ---------------------------------------------------------------------------
__global__ __attribute__((amdgpu_flat_work_group_size(512, 512)))
           __attribute__((amdgpu_waves_per_eu(2, 2)))
void lstm_kernel(
    const f16* __restrict__ xbuf,      // [256][64][16][8]
    const signed char* __restrict__ Wq,// [8][1024][32] i8
    const f16* __restrict__ Wxk,       // [1024][8]
    const float* __restrict__ bsum_p,  // [1024]
    const float* __restrict__ scd,     // [1024]  mx/127^2
    float* __restrict__ hnbuf) {       // [B][256] fp32
  const int tid = threadIdx.x;
  const int l   = tid & 63;
  const int w   = tid >> 6;             // wave 0..7
  const int l15 = l & 15;
  const int lg  = l >> 4;               // 0..3
  const int b0  = blockIdx.x << 4;      // 16 batches per block

  __shared__ f16 xall[64 * 16 * 8];          // 16384 B  [t][bi][8]
  __shared__ f16 Bx_s[1024 * 8];             // 16384 B  [p][8]
  __shared__ signed char hq_s[8 * 16 * 40];  //  5120 B  [kt][b][40-pad]
  __shared__ float wmax_s[8];

  // --- one-time staging ---
  {
    const f16x8* sx = (const f16x8*)Wxk;
    f16x8* dx = (f16x8*)Bx_s;
    for (int i = tid; i < 1024; i += 512) dx[i] = sx[i];
    const f16x8* sa = (const f16x8*)(xbuf + (size_t)blockIdx.x * 8192);
    f16x8* da = (f16x8*)xall;
    for (int i = tid; i < 1024; i += 512) da[i] = sa[i];
    for (int i = tid; i < 1280; i += 512) ((int*)hq_s)[i] = 0;
  }

  // --- per-lane column constants (8 cols: p = w*128 + ct*16 + l15) ---
  float biasv[8], scv[8];
  #pragma unroll
  for (int ct = 0; ct < 8; ++ct) {
    const int p = w * 128 + ct * 16 + l15;
    biasv[ct] = bsum_p[p];
    scv[ct]   = scd[p];
  }

  // --- persistent i8 B fragments, all 8 k-tiles -> AGPR file (128 regs) ---
  const int qbase = (w * 128 + l15) * 32 + lg * 8;
  long Bq[8][8];
  #pragma unroll
  for (int kt = 0; kt < 8; ++kt)
    #pragma unroll
    for (int ct = 0; ct < 8; ++ct)
      Bq[kt][ct] = *(const long*)(Wq + kt * 32768 + ct * 512 + qbase);

  const int hrd = l15 * 40 + lg * 8;    // A-frag read base (+kt*640)

  float c_[2][4];
  #pragma unroll
  for (int uh = 0; uh < 2; ++uh)
    #pragma unroll
    for (int q = 0; q < 4; ++q) c_[uh][q] = 0.f;

  float sh_prev = 1.f;

  __syncthreads();   // staging visible

  #pragma unroll 1
  for (int t = 0; t < 64; ++t) {
    // opaque zero defeats LICM on loop-invariant LDS reads
    int z = 0;
    asm volatile("" : "+v"(z));

    // pin the i8 weight fragments in the AGPR file (not re-loadable, not
    // copyable per-iteration: MFMA consumes B from AGPR directly)
    #pragma unroll
    for (int kt = 0; kt < 8; ++kt)
      #pragma unroll
      for (int ct = 0; ct < 8; ++ct)
        asm volatile("" : "+a"(Bq[kt][ct]));

    // x A-fragment: row=batch=l15, k=lg*8+j valid only for lg==0
    f16x8 ax = {(f16)0.f,(f16)0.f,(f16)0.f,(f16)0.f,
                (f16)0.f,(f16)0.f,(f16)0.f,(f16)0.f};
    if (lg == 0) ax = *(const f16x8*)&xall[(t * 16 + l15) * 8 + z];

    // hq @ Wq : 64 i8 MFMAs, B from AGPRs, acc from zero
    i32x4 acc[8];
    #pragma unroll
    for (int ct = 0; ct < 8; ++ct) acc[ct] = (i32x4){0, 0, 0, 0};
    #pragma unroll
    for (int kt = 0; kt < 8; ++kt) {
      const long Af = *(const long*)&hq_s[kt * 640 + hrd];
      #pragma unroll
      for (int ct = 0; ct < 8; ++ct)
        acc[ct] = __builtin_amdgcn_mfma_i32_16x16x32_i8(Af, Bq[kt][ct], acc[ct], 0, 0, 0);
    }

    // combine: facc = cvt(acc)*(mx*sh/127^2) + (bias + x@W_ih)
    f32x4 facc[8];
    #pragma unroll
    for (int ct = 0; ct < 8; ++ct) {
      f32x4 accF = (f32x4){biasv[ct], biasv[ct], biasv[ct], biasv[ct]};
      const f16x8 Bv = *(const f16x8*)(Bx_s + (w * 128 + ct * 16 + l15) * 8 + z);
      accF = __builtin_amdgcn_mfma_f32_16x16x32_f16(ax, Bv, accF, 0, 0, 0);
      const float s2 = scv[ct] * sh_prev;
      #pragma unroll
      for (int e = 0; e < 4; ++e)
        facc[ct][e] = (float)acc[ct][e] * s2 + accF[e];
    }

    // gates + h, track block max|h|
    float hv[2][4];
    float mloc = 0.f;
    #pragma unroll
    for (int uh = 0; uh < 2; ++uh) {
      #pragma unroll
      for (int q = 0; q < 4; ++q) {
        const float gi = facc[0 + uh][q];
        const float gf = facc[2 + uh][q];
        const float gg = facc[4 + uh][q];
        const float go = facc[6 + uh][q];
        const float cn = sigm_(gf) * c_[uh][q] + sigm_(gi) * tanh_(gg);
        c_[uh][q] = cn;
        const float h = sigm_(go) * tanh_(cn);
        hv[uh][q] = h;
        mloc = fmaxf(mloc, fabsf(h));
      }
    }
    #pragma unroll
    for (int off = 32; off; off >>= 1)
      mloc = fmaxf(mloc, __shfl_xor(mloc, off));
    if (l == 0) wmax_s[w] = mloc;

    __syncthreads();   // hq reads done; wave maxes visible

    float sh = 1e-8f;
    #pragma unroll
    for (int j = 0; j < 8; ++j) sh = fmaxf(sh, wmax_s[j]);
    const float qs = 127.f / sh;

    // quantize h and publish; write hn at final step
    #pragma unroll
    for (int uh = 0; uh < 2; ++uh) {
      const int wbq = w * 640 + uh * 16 + l15;
      const int u   = w * 32 + uh * 16 + l15;
      #pragma unroll
      for (int q = 0; q < 4; ++q) {
        const int b = lg * 4 + q;
        hq_s[wbq + b * 40] = (signed char)(int)rintf(hv[uh][q] * qs);
        if (t == 63) hnbuf[(size_t)(b0 + b) * H_ + u] = hv[uh][q];
      }
    }
    sh_prev = sh;
    __syncthreads();   // hq writes visible
  }
}

// ---------------------------------------------------------------------------
// Kernel 3: fused MLP head. 256 blocks x 512 threads, 16 batches per block.
// Dynamic LDS: a0 16x264 + a1 16x512 + a2 16x512 = 82432 B.
// ---------------------------------------------------------------------------
__global__ __launch_bounds__(512) void mlp_kernel(
    const float* __restrict__ selfb, const float* __restrict__ hnbuf,
    const float* __restrict__ W1, const float* __restrict__ b1,
    const float* __restrict__ W2, const float* __restrict__ b2,
    const float* __restrict__ Wv, const float* __restrict__ bv,
    float* __restrict__ out) {
  const int tid = threadIdx.x;
  const int b0  = blockIdx.x << 4;      // 16 batches per block
  const int tb  = tid >> 7;             // 0..3 (batch group)
  const int tn  = tid & 127;            // float4 column group (N=512 -> 128)

  extern __shared__ char smem[];
  float* a0 = (float*)smem;                    // [16][264]
  float* a1 = (float*)(smem + 16896);          // [16][512]
  float* a2 = (float*)(smem + 16896 + 32768);  // [16][512]

  for (int i = tid; i < 16 * SS_; i += 512)
    a0[(i / SS_) * 264 + (i % SS_)] = selfb[b0 * SS_ + i];
  for (int i = tid; i < 16 * H_; i += 512)
    a0[(i >> 8) * 264 + SS_ + (i & 255)] = hnbuf[((size_t)b0 << 8) + i];
  __syncthreads();

  float4 acc[4];

  { // layer 1: K=261, N=512
    const float4* W14 = (const float4*)W1;
    const float4 bb = ((const float4*)b1)[tn];
    #pragma unroll
    for (int q = 0; q < 4; ++q) acc[q] = bb;
    for (int k = 0; k < SS_ + H_; ++k) {
      const float4 w0 = W14[k * 128 + tn];
      #pragma unroll
      for (int q = 0; q < 4; ++q)
        fma4(acc[q], a0[(tb * 4 + q) * 264 + k], w0);
    }
    #pragma unroll
    for (int q = 0; q < 4; ++q)
      *(float4*)&a1[(tb * 4 + q) * 512 + tn * 4] = relu4(acc[q]);
  }
  __syncthreads();

  { // layer 2: K=512, N=512
    const float4* W24 = (const float4*)W2;
    const float4 bb = ((const float4*)b2)[tn];
    #pragma unroll
    for (int q = 0; q < 4; ++q) acc[q] = bb;
    for (int k = 0; k < M1_; ++k) {
      const float4 w0 = W24[k * 128 + tn];
      #pragma unroll
      for (int q = 0; q < 4; ++q)
        fma4(acc[q], a1[(tb * 4 + q) * 512 + k], w0);
    }
    #pragma unroll
    for (int q = 0; q < 4; ++q)
      *(float4*)&a2[(tb * 4 + q) * 512 + tn * 4] = relu4(acc[q]);
  }
  __syncthreads();

  // layer 3: K=512, N=81
  for (int idx = tid; idx < 16 * A_; idx += 512) {
    const int bi = idx / A_;
    const int n  = idx - bi * A_;
    float sum = bv[n];
    for (int k = 0; k < M2_; ++k)
      sum = fmaf(a2[bi * 512 + k], Wv[k * A_ + n], sum);
    out[(size_t)(b0 + bi) * A_ + n] = sum;
  }
}

// ---------------------------------------------------------------------------
extern "C" void kernel_launch(void* const* d_in, const int* in_sizes, int n_in,
                              void* d_out, int out_size, void* d_ws, size_t ws_size,
                              hipStream_t stream) {
  const float* state = (const float*)d_in[0];
  const float* W_ih  = (const float*)d_in[1];
  const float* W_hh  = (const float*)d_in[2];
  const float* b_ih  = (const float*)d_in[3];
  const float* b_hh  = (const float*)d_in[4];
  const float* W1    = (const float*)d_in[5];
  const float* b1    = (const float*)d_in[6];
  const float* W2    = (const float*)d_in[7];
  const float* b2    = (const float*)d_in[8];
  const float* Wv    = (const float*)d_in[9];
  const float* bv    = (const float*)d_in[10];
  float* out = (float*)d_out;

  // workspace layout (bytes, 16B-aligned); total ~8.76 MB
  char* ws = (char*)d_ws;
  signed char* Wq = (signed char*)(ws);        // 8*1024*32 i8  = 262144 B
  f16*   Wxk     = (f16*)(ws + 262144);        // 1024*8 f16    = 16384 B
  float* bsum_p  = (float*)(ws + 278528);      // 1024 f32      = 4096 B
  float* scd     = (float*)(ws + 282624);      // 1024 f32      = 4096 B
  f16*   xbuf    = (f16*)(ws + 290816);        // 256*64*16*8 f16 = 4194304 B
  float* selfb   = (float*)(ws + 4485120);     // 4096*5 f32    = 81920 B
  float* hnbuf   = (float*)(ws + 4567040);     // 4096*256 f32  = 4194304 B

  pack_weights<<<dim3(64), dim3(1024), 0, stream>>>(W_ih, W_hh, b_ih, b_hh,
                                                    Wq, Wxk, bsum_p, scd);
  sort_gather<<<dim3(B_), dim3(64), 0, stream>>>(state, xbuf, selfb);
  lstm_kernel<<<dim3(B_ / 16), dim3(512), 0, stream>>>(xbuf, Wq, Wxk, bsum_p,
                                                       scd, hnbuf);
  mlp_kernel<<<dim3(B_ / 16), dim3(512), 82432, stream>>>(selfb, hnbuf, W1, b1,
                                                          W2, b2, Wv, bv, out);
}

// Round 12
// 388.579 us; speedup vs baseline: 1.0277x; 1.0277x over previous
//
#include <hip/hip_runtime.h>
#include <math.h>

// Problem constants
#define B_   4096
#define N_   64
#define SS_  5
#define I_   7
#define H_   256
#define M1_  512
#define M2_  512
#define A_   81

typedef _Float16 f16;
typedef f16   f16x8 __attribute__((ext_vector_type(8)));
typedef float f32x4 __attribute__((ext_vector_type(4)));
typedef int   i32x4 __attribute__((ext_vector_type(4)));

__device__ __forceinline__ void fma4(float4& a, float s, const float4 w) {
  a.x = fmaf(s, w.x, a.x);
  a.y = fmaf(s, w.y, a.y);
  a.z = fmaf(s, w.z, a.z);
  a.w = fmaf(s, w.w, a.w);
}

__device__ __forceinline__ float4 relu4(float4 v) {
  v.x = fmaxf(v.x, 0.f); v.y = fmaxf(v.y, 0.f);
  v.z = fmaxf(v.z, 0.f); v.w = fmaxf(v.w, 0.f);
  return v;
}

__device__ __forceinline__ float sigm_(float x) {
  return __builtin_amdgcn_rcpf(1.f + __expf(-x));
}
__device__ __forceinline__ float tanh_(float x) {
  return 1.f - 2.f * __builtin_amdgcn_rcpf(__expf(2.f * x) + 1.f);
}

// ---------------------------------------------------------------------------
// Kernel 0: pack weights. One WAVE per packed column p (1024 waves).
// p = w*128 + ct*16 + l15 view; gate decomposition p = w*128 + g*32 + uu.
// Wq[kt][p][k32] i8 with per-column scale mx = max|col|:
//   Wq = round(W * 127/mx)            (W ≈ Wq·mx/127)
// scd[p]    = mx/127^2                (i32 -> gate dequant, × sh)
// bsum_p[p] = b_ih+b_hh;  Wxk[p][8] f16 x-weights (j<7 real, j=7 zero).
// ---------------------------------------------------------------------------
__global__ __launch_bounds__(1024) void pack_weights(
    const float* __restrict__ W_ih,
    const float* __restrict__ W_hh,
    const float* __restrict__ b_ih,
    const float* __restrict__ b_hh,
    signed char* __restrict__ Wq,
    f16* __restrict__ Wxk,
    float* __restrict__ bsum_p,
    float* __restrict__ scd) {
  const int gtid = blockIdx.x * 1024 + threadIdx.x;
  const int p    = gtid >> 6;           // one wave per column
  const int lane = gtid & 63;
  const int w = p >> 7, r = p & 127, g = r >> 5, uu = r & 31;
  const int row = g * H_ + w * 32 + uu;

  // lane owns k = lane*4 .. lane*4+3 (coalesced float4)
  const float4 v4 = *(const float4*)(W_hh + row * H_ + lane * 4);
  float mx = fmaxf(fmaxf(fabsf(v4.x), fabsf(v4.y)),
                   fmaxf(fabsf(v4.z), fabsf(v4.w)));
  #pragma unroll
  for (int off = 32; off; off >>= 1)
    mx = fmaxf(mx, __shfl_xor(mx, off));
  mx = fmaxf(mx, 1e-12f);
  const float is = 127.f / mx;

  // quantize own 4 values, pack to one dword
  int b0i = (int)rintf(v4.x * is), b1i = (int)rintf(v4.y * is);
  int b2i = (int)rintf(v4.z * is), b3i = (int)rintf(v4.w * is);
  b0i = max(-127, min(127, b0i)); b1i = max(-127, min(127, b1i));
  b2i = max(-127, min(127, b2i)); b3i = max(-127, min(127, b3i));
  const unsigned int packed = (b0i & 0xff) | ((b1i & 0xff) << 8) |
                              ((b2i & 0xff) << 16) | ((b3i & 0xff) << 24);
  const int kt  = lane >> 3;            // (lane*4)/32
  const int k32 = (lane & 7) * 4;
  *(unsigned int*)(Wq + kt * 32768 + p * 32 + k32) = packed;

  if (lane < 8)  Wxk[p * 8 + lane] = (lane < I_) ? (f16)W_ih[row * I_ + lane] : (f16)0.f;
  if (lane == 8)  bsum_p[p]  = b_ih[row] + b_hh[row];
  if (lane == 9)  scd[p]     = mx * (1.f / 16129.f);   // mx/127^2
}

// ---------------------------------------------------------------------------
// Kernel 1: distance + stable descending rank-sort + gather.
// xbuf: f16 [blk][rank(64)][bi(16)][8]; selfbuf: f32 [B][5].
// ---------------------------------------------------------------------------
__global__ void sort_gather(const float* __restrict__ state,
                            f16* __restrict__ xbuf,
                            float* __restrict__ selfbuf) {
  const int b = blockIdx.x;
  const int e = threadIdx.x;                 // 0..63, one wave
  const float* row = state + ((size_t)b * N_ + e) * 12;
  const float4* r4 = (const float4*)row;
  const float4 v0 = r4[0], v1 = r4[1], v2 = r4[2];
  float s[12];
  s[0]=v0.x; s[1]=v0.y; s[2]=v0.z;  s[3]=v0.w;
  s[4]=v1.x; s[5]=v1.y; s[6]=v1.z;  s[7]=v1.w;
  s[8]=v2.x; s[9]=v2.y; s[10]=v2.z; s[11]=v2.w;

  const float s5 = s[5], s6 = s[6];
  const float d = (s5 != 0.f && s6 != 0.f) ? sqrtf(s5 * s5 + s6 * s6) : INFINITY;

  __shared__ float dd[64];
  dd[e] = d;
  __syncthreads();

  int rank = 0;
  #pragma unroll
  for (int j = 0; j < 64; ++j) {
    const float dj = dd[j];
    rank += (dj > d || (dj == d && j < e)) ? 1 : 0;
  }

  f16* xo = xbuf + (((size_t)(b >> 4) * 64 + rank) * 16 + (b & 15)) * 8;
  #pragma unroll
  for (int f = 0; f < I_; ++f) xo[f] = (f16)s[SS_ + f];
  xo[7] = (f16)0.f;

  if (e == 0) {
    #pragma unroll
    for (int i = 0; i < SS_; ++i) selfbuf[b * SS_ + i] = s[i];
  }
}

// ---------------------------------------------------------------------------
// Kernel 2: i8 MFMA LSTM, AGPR-resident W_hh (one-time pin + builtin MFMA).
// 256 blocks x 512 threads (8 waves = 2/SIMD, 1 block/CU), 16 batches/blk.
// Wave w owns packed cols [128w,128w+128): all 8 k-tiles pinned ONCE into
// AGPRs via "+a" asm BEFORE the loop (def is opaque -> cannot be re-
// materialized/sunk); in-loop MFMA uses the BUILTIN, whose A/B operands are
// AV-class on gfx950 and read AGPR directly (no copies, alignment correct —
// R11's raw-asm misaligned-D bug avoided). Budget/wave: 128 AGPR + ~115
// VGPR = 243 <= 256 at 2 waves/SIMD. h quantized i8, per-block per-step
// dynamic scale. Gates: facc = cvt(i32acc)·(mx·sh/127^2) + (bias + x@W_ih).
// LDS: xall 16384 + Bx 16384 + hq 5120 + wmax 32 = ~37.9 KB.
// ---------------------------------------------------------------------------
__global__ __attribute__((amdgpu_flat_work_group_size(512, 512)))
           __attribute__((amdgpu_waves_per_eu(2, 2)))
void lstm_kernel(
    const f16* __restrict__ xbuf,      // [256][64][16][8]
    const signed char* __restrict__ Wq,// [8][1024][32] i8
    const f16* __restrict__ Wxk,       // [1024][8]
    const float* __restrict__ bsum_p,  // [1024]
    const float* __restrict__ scd,     // [1024]  mx/127^2
    float* __restrict__ hnbuf) {       // [B][256] fp32
  const int tid = threadIdx.x;
  const int l   = tid & 63;
  const int w   = tid >> 6;             // wave 0..7
  const int l15 = l & 15;
  const int lg  = l >> 4;               // 0..3
  const int b0  = blockIdx.x << 4;      // 16 batches per block

  __shared__ f16 xall[64 * 16 * 8];          // 16384 B  [t][bi][8]
  __shared__ f16 Bx_s[1024 * 8];             // 16384 B  [p][8]
  __shared__ signed char hq_s[8 * 16 * 40];  //  5120 B  [kt][b][40-pad]
  __shared__ float wmax_s[8];

  // --- one-time staging ---
  {
    const f16x8* sx = (const f16x8*)Wxk;
    f16x8* dx = (f16x8*)Bx_s;
    for (int i = tid; i < 1024; i += 512) dx[i] = sx[i];
    const f16x8* sa = (const f16x8*)(xbuf + (size_t)blockIdx.x * 8192);
    f16x8* da = (f16x8*)xall;
    for (int i = tid; i < 1024; i += 512) da[i] = sa[i];
    for (int i = tid; i < 1280; i += 512) ((int*)hq_s)[i] = 0;
  }

  // --- per-lane column constants (8 cols: p = w*128 + ct*16 + l15) ---
  float biasv[8], scv[8];
  #pragma unroll
  for (int ct = 0; ct < 8; ++ct) {
    const int p = w * 128 + ct * 16 + l15;
    biasv[ct] = bsum_p[p];
    scv[ct]   = scd[p];
  }

  // --- persistent i8 B fragments -> AGPR file, pinned ONCE (128 AGPRs).
  // The asm defines the value (opaque): the load cannot be sunk into the
  // loop, and builtin MFMA consumes AGPR operands directly (AV class).
  const int qbase = (w * 128 + l15) * 32 + lg * 8;
  long Bq[8][8];
  #pragma unroll
  for (int kt = 0; kt < 8; ++kt)
    #pragma unroll
    for (int ct = 0; ct < 8; ++ct) {
      Bq[kt][ct] = *(const long*)(Wq + kt * 32768 + ct * 512 + qbase);
      asm volatile("" : "+a"(Bq[kt][ct]));   // one-time move into AGPR
    }

  const int hrd = l15 * 40 + lg * 8;    // A-frag read base (+kt*640)

  float c_[2][4];
  #pragma unroll
  for (int uh = 0; uh < 2; ++uh)
    #pragma unroll
    for (int q = 0; q < 4; ++q) c_[uh][q] = 0.f;

  float sh_prev = 1.f;

  __syncthreads();   // staging visible

  #pragma unroll 1
  for (int t = 0; t < 64; ++t) {
    // opaque zero defeats LICM on loop-invariant LDS reads
    int z = 0;
    asm volatile("" : "+v"(z));

    // x A-fragment: row=batch=l15, k=lg*8+j valid only for lg==0
    f16x8 ax = {(f16)0.f,(f16)0.f,(f16)0.f,(f16)0.f,
                (f16)0.f,(f16)0.f,(f16)0.f,(f16)0.f};
    if (lg == 0) ax = *(const f16x8*)&xall[(t * 16 + l15) * 8 + z];

    // hq @ Wq : 64 i8 MFMAs (builtin, B from AGPR), acc from zero
    i32x4 acc[8];
    #pragma unroll
    for (int ct = 0; ct < 8; ++ct) acc[ct] = (i32x4){0, 0, 0, 0};
    #pragma unroll
    for (int kt = 0; kt < 8; ++kt) {
      const long Af = *(const long*)&hq_s[kt * 640 + hrd];
      #pragma unroll
      for (int ct = 0; ct < 8; ++ct)
        acc[ct] = __builtin_amdgcn_mfma_i32_16x16x32_i8(Af, Bq[kt][ct], acc[ct], 0, 0, 0);
    }

    // combine: facc = cvt(acc)*(mx*sh/127^2) + (bias + x@W_ih)
    f32x4 facc[8];
    #pragma unroll
    for (int ct = 0; ct < 8; ++ct) {
      f32x4 accF = (f32x4){biasv[ct], biasv[ct], biasv[ct], biasv[ct]};
      const f16x8 Bv = *(const f16x8*)(Bx_s + (w * 128 + ct * 16 + l15) * 8 + z);
      accF = __builtin_amdgcn_mfma_f32_16x16x32_f16(ax, Bv, accF, 0, 0, 0);
      const float s2 = scv[ct] * sh_prev;
      #pragma unroll
      for (int e = 0; e < 4; ++e)
        facc[ct][e] = (float)acc[ct][e] * s2 + accF[e];
    }

    // gates + h, track block max|h|
    float hv[2][4];
    float mloc = 0.f;
    #pragma unroll
    for (int uh = 0; uh < 2; ++uh) {
      #pragma unroll
      for (int q = 0; q < 4; ++q) {
        const float gi = facc[0 + uh][q];
        const float gf = facc[2 + uh][q];
        const float gg = facc[4 + uh][q];
        const float go = facc[6 + uh][q];
        const float cn = sigm_(gf) * c_[uh][q] + sigm_(gi) * tanh_(gg);
        c_[uh][q] = cn;
        const float h = sigm_(go) * tanh_(cn);
        hv[uh][q] = h;
        mloc = fmaxf(mloc, fabsf(h));
      }
    }
    #pragma unroll
    for (int off = 32; off; off >>= 1)
      mloc = fmaxf(mloc, __shfl_xor(mloc, off));
    if (l == 0) wmax_s[w] = mloc;

    __syncthreads();   // hq reads done; wave maxes visible

    float sh = 1e-8f;
    #pragma unroll
    for (int j = 0; j < 8; ++j) sh = fmaxf(sh, wmax_s[j]);
    const float qs = 127.f / sh;

    // quantize h and publish; write hn at final step
    #pragma unroll
    for (int uh = 0; uh < 2; ++uh) {
      const int wbq = w * 640 + uh * 16 + l15;
      const int u   = w * 32 + uh * 16 + l15;
      #pragma unroll
      for (int q = 0; q < 4; ++q) {
        const int b = lg * 4 + q;
        hq_s[wbq + b * 40] = (signed char)(int)rintf(hv[uh][q] * qs);
        if (t == 63) hnbuf[(size_t)(b0 + b) * H_ + u] = hv[uh][q];
      }
    }
    sh_prev = sh;
    __syncthreads();   // hq writes visible
  }

  // post-loop consumer: keeps the whole live range AGPR-classified
  #pragma unroll
  for (int kt = 0; kt < 8; ++kt)
    #pragma unroll
    for (int ct = 0; ct < 8; ++ct)
      asm volatile("" :: "a"(Bq[kt][ct]));
}

// ---------------------------------------------------------------------------
// Kernel 3: fused MLP head. 256 blocks x 512 threads, 16 batches per block.
// Dynamic LDS: a0 16x264 + a1 16x512 + a2 16x512 = 82432 B.
// ---------------------------------------------------------------------------
__global__ __launch_bounds__(512) void mlp_kernel(
    const float* __restrict__ selfb, const float* __restrict__ hnbuf,
    const float* __restrict__ W1, const float* __restrict__ b1,
    const float* __restrict__ W2, const float* __restrict__ b2,
    const float* __restrict__ Wv, const float* __restrict__ bv,
    float* __restrict__ out) {
  const int tid = threadIdx.x;
  const int b0  = blockIdx.x << 4;      // 16 batches per block
  const int tb  = tid >> 7;             // 0..3 (batch group)
  const int tn  = tid & 127;            // float4 column group (N=512 -> 128)

  extern __shared__ char smem[];
  float* a0 = (float*)smem;                    // [16][264]
  float* a1 = (float*)(smem + 16896);          // [16][512]
  float* a2 = (float*)(smem + 16896 + 32768);  // [16][512]

  for (int i = tid; i < 16 * SS_; i += 512)
    a0[(i / SS_) * 264 + (i % SS_)] = selfb[b0 * SS_ + i];
  for (int i = tid; i < 16 * H_; i += 512)
    a0[(i >> 8) * 264 + SS_ + (i & 255)] = hnbuf[((size_t)b0 << 8) + i];
  __syncthreads();

  float4 acc[4];

  { // layer 1: K=261, N=512
    const float4* W14 = (const float4*)W1;
    const float4 bb = ((const float4*)b1)[tn];
    #pragma unroll
    for (int q = 0; q < 4; ++q) acc[q] = bb;
    for (int k = 0; k < SS_ + H_; ++k) {
      const float4 w0 = W14[k * 128 + tn];
      #pragma unroll
      for (int q = 0; q < 4; ++q)
        fma4(acc[q], a0[(tb * 4 + q) * 264 + k], w0);
    }
    #pragma unroll
    for (int q = 0; q < 4; ++q)
      *(float4*)&a1[(tb * 4 + q) * 512 + tn * 4] = relu4(acc[q]);
  }
  __syncthreads();

  { // layer 2: K=512, N=512
    const float4* W24 = (const float4*)W2;
    const float4 bb = ((const float4*)b2)[tn];
    #pragma unroll
    for (int q = 0; q < 4; ++q) acc[q] = bb;
    for (int k = 0; k < M1_; ++k) {
      const float4 w0 = W24[k * 128 + tn];
      #pragma unroll
      for (int q = 0; q < 4; ++q)
        fma4(acc[q], a1[(tb * 4 + q) * 512 + k], w0);
    }
    #pragma unroll
    for (int q = 0; q < 4; ++q)
      *(float4*)&a2[(tb * 4 + q) * 512 + tn * 4] = relu4(acc[q]);
  }
  __syncthreads();

  // layer 3: K=512, N=81
  for (int idx = tid; idx < 16 * A_; idx += 512) {
    const int bi = idx / A_;
    const int n  = idx - bi * A_;
    float sum = bv[n];
    for (int k = 0; k < M2_; ++k)
      sum = fmaf(a2[bi * 512 + k], Wv[k * A_ + n], sum);
    out[(size_t)(b0 + bi) * A_ + n] = sum;
  }
}

// ---------------------------------------------------------------------------
extern "C" void kernel_launch(void* const* d_in, const int* in_sizes, int n_in,
                              void* d_out, int out_size, void* d_ws, size_t ws_size,
                              hipStream_t stream) {
  const float* state = (const float*)d_in[0];
  const float* W_ih  = (const float*)d_in[1];
  const float* W_hh  = (const float*)d_in[2];
  const float* b_ih  = (const float*)d_in[3];
  const float* b_hh  = (const float*)d_in[4];
  const float* W1    = (const float*)d_in[5];
  const float* b1    = (const float*)d_in[6];
  const float* W2    = (const float*)d_in[7];
  const float* b2    = (const float*)d_in[8];
  const float* Wv    = (const float*)d_in[9];
  const float* bv    = (const float*)d_in[10];
  float* out = (float*)d_out;

  // workspace layout (bytes, 16B-aligned); total ~8.76 MB
  char* ws = (char*)d_ws;
  signed char* Wq = (signed char*)(ws);        // 8*1024*32 i8  = 262144 B
  f16*   Wxk     = (f16*)(ws + 262144);        // 1024*8 f16    = 16384 B
  float* bsum_p  = (float*)(ws + 278528);      // 1024 f32      = 4096 B
  float* scd     = (float*)(ws + 282624);      // 1024 f32      = 4096 B
  f16*   xbuf    = (f16*)(ws + 290816);        // 256*64*16*8 f16 = 4194304 B
  float* selfb   = (float*)(ws + 4485120);     // 4096*5 f32    = 81920 B
  float* hnbuf   = (float*)(ws + 4567040);     // 4096*256 f32  = 4194304 B

  pack_weights<<<dim3(64), dim3(1024), 0, stream>>>(W_ih, W_hh, b_ih, b_hh,
                                                    Wq, Wxk, bsum_p, scd);
  sort_gather<<<dim3(B_), dim3(64), 0, stream>>>(state, xbuf, selfb);
  lstm_kernel<<<dim3(B_ / 16), dim3(512), 0, stream>>>(xbuf, Wq, Wxk, bsum_p,
                                                       scd, hnbuf);
  mlp_kernel<<<dim3(B_ / 16), dim3(512), 82432, stream>>>(selfb, hnbuf, W1, b1,
                                                          W2, b2, Wv, bv, out);
}